// Round 1
// baseline (562.069 us; speedup 1.0000x reference)
//
#include <hip/hip_runtime.h>
#include <math.h>

#define N_NODES 50000
#define N_EDGES 800000
#define EB 16   // edges per batch (16 lanes per edge, 256 threads)
#define NB 8    // batches per block

__device__ __forceinline__ void atomicMaxFloat(float* addr, float val) {
    if (val >= 0.0f)
        atomicMax((int*)addr, __float_as_int(val));
    else
        atomicMin((unsigned int*)addr, __float_as_uint(val));
}

__global__ __launch_bounds__(256) void init_kernel(float* __restrict__ amax,
                                                   float* __restrict__ den,
                                                   float* __restrict__ agg) {
    int i = blockIdx.x * 256 + threadIdx.x;   // 0 .. N*64-1 (exact)
    agg[i] = 0.0f;
    if (i < N_NODES * 4) {
        amax[i] = -INFINITY;
        den[i] = 0.0f;
    }
}

// Per-node-type linear projections K, Q, V. One wave (64 lanes) per node.
__global__ __launch_bounds__(256) void kqv_kernel(
    const float* __restrict__ x, const int* __restrict__ ntype,
    const float* __restrict__ Wk, const float* __restrict__ bk,
    const float* __restrict__ Wq, const float* __restrict__ bq,
    const float* __restrict__ Wv, const float* __restrict__ bv,
    float* __restrict__ Kn, float* __restrict__ Qn, float* __restrict__ Vn)
{
    __shared__ float xs[4][64];
    int g = threadIdx.x >> 6;
    int j = threadIdx.x & 63;
    int node = blockIdx.x * 4 + g;          // exact: 12500*4 = 50000
    xs[g][j] = x[node * 64 + j];
    __builtin_amdgcn_wave_barrier();        // wave-local buffer, same wave
    int t = ntype[node];
    const float* wk = Wk + t * 4096;
    const float* wq = Wq + t * 4096;
    const float* wv = Wv + t * 4096;
    float sk = bk[t * 64 + j];
    float sq = bq[t * 64 + j];
    float sv = bv[t * 64 + j];
#pragma unroll
    for (int i = 0; i < 64; ++i) {
        float xi = xs[g][i];
        sk = fmaf(xi, wk[i * 64 + j], sk);
        sq = fmaf(xi, wq[i * 64 + j], sq);
        sv = fmaf(xi, wv[i * 64 + j], sv);
    }
    Kn[node * 64 + j] = sk;
    Qn[node * 64 + j] = sq;
    Vn[node * 64 + j] = sv;
}

// Attention scores: att[e][h] = (q . (k @ rel_att[r])) * pri[r][h] / sqrt(D)
// 16 lanes per edge; lane l owns column l of each head's 16x16 transform.
__global__ __launch_bounds__(256) void edge_att_kernel(
    const float* __restrict__ Qn, const float* __restrict__ Kn,
    const int* __restrict__ ei, const int* __restrict__ et,
    const float* __restrict__ rel_att, const float* __restrict__ rel_pri,
    float* __restrict__ att, float* __restrict__ amax)
{
    __shared__ float kbuf[EB][68];          // +4 pad: conflict-free b128 broadcasts
    int g = threadIdx.x >> 4;
    int l = threadIdx.x & 15;
    for (int b = 0; b < NB; ++b) {
        int e = (blockIdx.x * NB + b) * EB + g;   // exact: 6250*8*16 = 800000
        int src = ei[e];
        int tgt = ei[N_EDGES + e];
        int r = et[e];
#pragma unroll
        for (int h = 0; h < 4; ++h)
            kbuf[g][h * 16 + l] = Kn[src * 64 + h * 16 + l];
        __builtin_amdgcn_wave_barrier();    // group-local buffer, same wave
        const float* A = rel_att + r * 1024;
        float q[4], s[4];
#pragma unroll
        for (int h = 0; h < 4; ++h)
            q[h] = Qn[tgt * 64 + h * 16 + l];
#pragma unroll
        for (int h = 0; h < 4; ++h) {
            float k2 = 0.0f;
#pragma unroll
            for (int d = 0; d < 16; d += 4) {
                float4 kk = *(const float4*)&kbuf[g][h * 16 + d];
                k2 = fmaf(kk.x, A[(h * 16 + d + 0) * 16 + l], k2);
                k2 = fmaf(kk.y, A[(h * 16 + d + 1) * 16 + l], k2);
                k2 = fmaf(kk.z, A[(h * 16 + d + 2) * 16 + l], k2);
                k2 = fmaf(kk.w, A[(h * 16 + d + 3) * 16 + l], k2);
            }
            s[h] = q[h] * k2;
        }
#pragma unroll
        for (int m = 8; m >= 1; m >>= 1) {
            s[0] += __shfl_xor(s[0], m, 16);
            s[1] += __shfl_xor(s[1], m, 16);
            s[2] += __shfl_xor(s[2], m, 16);
            s[3] += __shfl_xor(s[3], m, 16);
        }
        if (l < 4) {
            float a = s[l] * rel_pri[r * 4 + l] * 0.25f;   // /sqrt(16)
            att[e * 4 + l] = a;
            atomicMaxFloat(&amax[tgt * 4 + l], a);
        }
        __builtin_amdgcn_wave_barrier();
    }
}

// ex = exp(att - amax[tgt]); den[tgt] += ex
__global__ __launch_bounds__(256) void edge_exp_kernel(
    const int* __restrict__ ei, float* __restrict__ att,
    const float* __restrict__ amax, float* __restrict__ den)
{
    int idx = blockIdx.x * 256 + threadIdx.x;   // e*4+h, exact 3.2M
    int e = idx >> 2, h = idx & 3;
    int tgt = ei[N_EDGES + e];
    float ex = __expf(att[idx] - amax[tgt * 4 + h]);
    att[idx] = ex;
    atomicAdd(&den[tgt * 4 + h], ex);
}

// msg = (v @ rel_msg[r]) * attw ; agg[tgt] += msg
__global__ __launch_bounds__(256) void edge_agg_kernel(
    const float* __restrict__ Vn, const int* __restrict__ ei,
    const int* __restrict__ et, const float* __restrict__ rel_msg,
    const float* __restrict__ att, const float* __restrict__ den,
    float* __restrict__ agg)
{
    __shared__ float vbuf[EB][68];
    int g = threadIdx.x >> 4;
    int l = threadIdx.x & 15;
    for (int b = 0; b < NB; ++b) {
        int e = (blockIdx.x * NB + b) * EB + g;
        int src = ei[e];
        int tgt = ei[N_EDGES + e];
        int r = et[e];
#pragma unroll
        for (int h = 0; h < 4; ++h)
            vbuf[g][h * 16 + l] = Vn[src * 64 + h * 16 + l];
        __builtin_amdgcn_wave_barrier();
        const float* M = rel_msg + r * 1024;
        float w[4];
#pragma unroll
        for (int h = 0; h < 4; ++h)
            w[h] = att[e * 4 + h] / den[tgt * 4 + h];
#pragma unroll
        for (int h = 0; h < 4; ++h) {
            float v2 = 0.0f;
#pragma unroll
            for (int d = 0; d < 16; d += 4) {
                float4 vv = *(const float4*)&vbuf[g][h * 16 + d];
                v2 = fmaf(vv.x, M[(h * 16 + d + 0) * 16 + l], v2);
                v2 = fmaf(vv.y, M[(h * 16 + d + 1) * 16 + l], v2);
                v2 = fmaf(vv.z, M[(h * 16 + d + 2) * 16 + l], v2);
                v2 = fmaf(vv.w, M[(h * 16 + d + 3) * 16 + l], v2);
            }
            atomicAdd(&agg[tgt * 64 + h * 16 + l], v2 * w[h]);
        }
        __builtin_amdgcn_wave_barrier();
    }
}

// gelu -> typed linear -> skip mix -> per-type LayerNorm. One wave per node.
__global__ __launch_bounds__(256) void final_kernel(
    const float* __restrict__ x, const int* __restrict__ ntype,
    const float* __restrict__ agg, const float* __restrict__ Wa,
    const float* __restrict__ ba, const float* __restrict__ ln_g,
    const float* __restrict__ ln_b, const float* __restrict__ skipw,
    float* __restrict__ out)
{
    __shared__ float gs[4][64];
    int g = threadIdx.x >> 6;
    int j = threadIdx.x & 63;
    int node = blockIdx.x * 4 + g;
    float a = agg[node * 64 + j];
    float ge = 0.5f * a * (1.0f + erff(a * 0.70710678118654752f));
    gs[g][j] = ge;
    __builtin_amdgcn_wave_barrier();        // wave-local buffer
    int t = ntype[node];
    const float* wa = Wa + t * 4096;
    float tr = ba[t * 64 + j];
#pragma unroll
    for (int i = 0; i < 64; ++i)
        tr = fmaf(gs[g][i], wa[i * 64 + j], tr);
    float sw = skipw[t];
    float sk = 1.0f / (1.0f + __expf(-sw));
    float res = tr * sk + x[node * 64 + j] * (1.0f - sk);
    float sum = res, sumsq = res * res;
#pragma unroll
    for (int m = 32; m >= 1; m >>= 1) {
        sum += __shfl_xor(sum, m, 64);
        sumsq += __shfl_xor(sumsq, m, 64);
    }
    float mu = sum * (1.0f / 64.0f);
    float var = sumsq * (1.0f / 64.0f) - mu * mu;
    float rn = (res - mu) * rsqrtf(var + 1e-5f);
    out[node * 64 + j] = rn * ln_g[t * 64 + j] + ln_b[t * 64 + j];
}

extern "C" void kernel_launch(void* const* d_in, const int* in_sizes, int n_in,
                              void* d_out, int out_size, void* d_ws, size_t ws_size,
                              hipStream_t stream) {
    const float* x        = (const float*)d_in[0];
    const int*   ntype    = (const int*)d_in[1];
    const int*   ei       = (const int*)d_in[2];
    const int*   et       = (const int*)d_in[3];
    const float* Wk       = (const float*)d_in[4];
    const float* bk       = (const float*)d_in[5];
    const float* Wq       = (const float*)d_in[6];
    const float* bq       = (const float*)d_in[7];
    const float* Wv       = (const float*)d_in[8];
    const float* bv       = (const float*)d_in[9];
    const float* Wa       = (const float*)d_in[10];
    const float* ba       = (const float*)d_in[11];
    const float* ln_g     = (const float*)d_in[12];
    const float* ln_b     = (const float*)d_in[13];
    const float* rel_pri  = (const float*)d_in[14];
    const float* rel_att  = (const float*)d_in[15];
    const float* rel_msg  = (const float*)d_in[16];
    const float* skipw    = (const float*)d_in[17];
    float* out = (float*)d_out;

    float* ws   = (float*)d_ws;
    float* Qn   = ws;                      // N*64
    float* Kn   = ws + 3200000;            // N*64
    float* Vn   = ws + 6400000;            // N*64
    float* att  = ws + 9600000;            // E*4
    float* amax = ws + 12800000;           // N*4
    float* den  = ws + 13000000;           // N*4
    float* agg  = ws + 13200000;           // N*64  (end: 16.4M floats = 65.6 MB)

    init_kernel<<<12500, 256, 0, stream>>>(amax, den, agg);
    kqv_kernel<<<12500, 256, 0, stream>>>(x, ntype, Wk, bk, Wq, bq, Wv, bv,
                                          Kn, Qn, Vn);
    edge_att_kernel<<<6250, 256, 0, stream>>>(Qn, Kn, ei, et, rel_att, rel_pri,
                                              att, amax);
    edge_exp_kernel<<<12500, 256, 0, stream>>>(ei, att, amax, den);
    edge_agg_kernel<<<6250, 256, 0, stream>>>(Vn, ei, et, rel_msg, att, den, agg);
    final_kernel<<<12500, 256, 0, stream>>>(x, ntype, agg, Wa, ba, ln_g, ln_b,
                                            skipw, out);
}